// Round 1
// 429.060 us; speedup vs baseline: 1.1188x; 1.1188x over previous
//
#include <hip/hip_runtime.h>

typedef __bf16 bf16x8 __attribute__((ext_vector_type(8)));
typedef float f32x4 __attribute__((ext_vector_type(4)));
typedef unsigned short u16x4 __attribute__((ext_vector_type(4)));
typedef unsigned short u16x8 __attribute__((ext_vector_type(8)));

#define KP 2112   // padded K: 2080 + 32 = 33 * 64
#define NT 33     // K-tiles of 64

__device__ __forceinline__ unsigned short f2bf(float f) {
  unsigned int u = __builtin_bit_cast(unsigned int, f);
  u += 0x7FFFu + ((u >> 16) & 1u);   // round-to-nearest-even
  return (unsigned short)(u >> 16);
}

__device__ __forceinline__ bf16x8 ld_frag(const unsigned short* p) {
  return __builtin_bit_cast(bf16x8, *(const u16x8*)p);
}

#define MFMA16(a, b, c) __builtin_amdgcn_mfma_f32_16x16x32_bf16((a), (b), (c), 0, 0, 0)

// async global->LDS, 16B per lane (global_load_lds_dwordx4)
__device__ __forceinline__ void cp16(const void* g, void* l) {
  __builtin_amdgcn_global_load_lds(
      (const __attribute__((address_space(1))) unsigned int*)g,
      (__attribute__((address_space(3))) unsigned int*)l, 16, 0, 0);
}

__device__ __forceinline__ void barrier_sync() {
  asm volatile("" ::: "memory");
  __builtin_amdgcn_s_barrier();
  __builtin_amdgcn_sched_barrier(0);
}

#define VMWAIT(N) asm volatile("s_waitcnt vmcnt(" #N ")" ::: "memory")

// ---------------------------------------------------------------------------
// fp32 [4096,2080] -> bf16 [4096,2112] with zero pad (for W_triu / W_tril)
// ---------------------------------------------------------------------------
__global__ __launch_bounds__(256) void cvt_pad(const float* __restrict__ in,
                                               unsigned short* __restrict__ out) {
  const int total = 4096 * (KP / 4);           // u16x4 chunks
  int i = blockIdx.x * 256 + threadIdx.x;
  const int stride = gridDim.x * 256;
  for (; i < total; i += stride) {
    const int row = i / (KP / 4);
    const int c4 = i - row * (KP / 4);
    u16x4 o = {0, 0, 0, 0};
    if (c4 < 520) {
      float4 v = *(const float4*)(in + (size_t)row * 2080 + c4 * 4);
      o[0] = f2bf(v.x); o[1] = f2bf(v.y); o[2] = f2bf(v.z); o[3] = f2bf(v.w);
    }
    ((u16x4*)out)[i] = o;
  }
}

// ---------------------------------------------------------------------------
// One-time: Wt[c*64+d] = bf16(W[d*64+c])  (shared by all 4096 batch_kp blocks)
// ---------------------------------------------------------------------------
__global__ __launch_bounds__(256) void prep_wt(const float* __restrict__ W,
                                               unsigned short* __restrict__ Wt) {
  const int tid = threadIdx.x;
#pragma unroll
  for (int j = 0; j < 16; ++j) {
    const int o = tid * 16 + j;           // 0..4095
    const int c = o >> 6, d = o & 63;
    Wt[o] = f2bf(W[d * 64 + c]);
  }
}

// ---------------------------------------------------------------------------
// Per-batch: embs_kp = E * kp_W * E^T via bf16 MFMA; copy E to out0;
// scatter triu/tril (bf16, K-stride 2112, pad zeroed).
// ---------------------------------------------------------------------------
__global__ __launch_bounds__(256) void batch_kp(
    const float* __restrict__ E,        // [B,64,64]
    const unsigned short* __restrict__ Wt,  // [64,64] bf16 transposed
    float* __restrict__ out0,           // [B,4096]
    unsigned short* __restrict__ triu,  // [B,2112] bf16
    unsigned short* __restrict__ tril)  // [B,2112] bf16
{
  __shared__ __align__(16) unsigned short sE[64 * 64];
  __shared__ __align__(16) unsigned short sWt[64 * 64];
  __shared__ __align__(16) unsigned short sT[64 * 64];

  const int b = blockIdx.x;
  const int tid = threadIdx.x;
  const float* Eb = E + (size_t)b * 4096;
  float* o0 = out0 + (size_t)b * 4096;

  cp16(Wt + tid * 8, sWt + tid * 8);
  cp16(Wt + 2048 + tid * 8, sWt + 2048 + tid * 8);

#pragma unroll
  for (int it = 0; it < 4; ++it) {
    const int flat = it * 1024 + tid * 4;
    float4 v = *(const float4*)(Eb + flat);
    *(float4*)(o0 + flat) = v;                 // embs_flatten output (exact fp32)
    u16x4 e;
    e[0] = f2bf(v.x); e[1] = f2bf(v.y); e[2] = f2bf(v.z); e[3] = f2bf(v.w);
    *(u16x4*)(sE + flat) = e;
  }
  __syncthreads();   // drains vmcnt (cp16) + lgkm

  const int lane = tid & 63, w = tid >> 6;
  const int fr = lane & 15;
  const int fk = (lane >> 4) << 3;
  const int qr = (lane >> 4) << 2;

  // T = Ebf * Wkp : wave w computes rows [w*16, w*16+16)
#pragma unroll
  for (int ct = 0; ct < 4; ++ct) {
    f32x4 acc = {0.f, 0.f, 0.f, 0.f};
#pragma unroll
    for (int k2 = 0; k2 < 2; ++k2) {
      bf16x8 a = ld_frag(sE + (w * 16 + fr) * 64 + k2 * 32 + fk);
      bf16x8 bb = ld_frag(sWt + (ct * 16 + fr) * 64 + k2 * 32 + fk);
      acc = MFMA16(a, bb, acc);
    }
#pragma unroll
    for (int r = 0; r < 4; ++r)
      sT[(w * 16 + qr + r) * 64 + ct * 16 + fr] = f2bf(acc[r]);
  }
  __syncthreads();

  // K = T * E^T ; scatter into triu/tril.
  unsigned short* tu = triu + (size_t)b * KP;
  unsigned short* tl = tril + (size_t)b * KP;
  if (tid < 32) { tu[2080 + tid] = 0; tl[2080 + tid] = 0; }  // zero K-pad
#pragma unroll
  for (int ct = 0; ct < 4; ++ct) {
    f32x4 acc = {0.f, 0.f, 0.f, 0.f};
#pragma unroll
    for (int k2 = 0; k2 < 2; ++k2) {
      bf16x8 a = ld_frag(sT + (w * 16 + fr) * 64 + k2 * 32 + fk);
      bf16x8 bb = ld_frag(sE + (ct * 16 + fr) * 64 + k2 * 32 + fk);
      acc = MFMA16(a, bb, acc);
    }
#pragma unroll
    for (int r = 0; r < 4; ++r) {
      const int i = w * 16 + qr + r;
      const int j = ct * 16 + fr;
      const unsigned short v = f2bf(acc[r]);
      if (j >= i) tu[i * 64 - ((i * (i - 1)) >> 1) + (j - i)] = v;
      if (j <= i) tl[((i * (i + 1)) >> 1) + j] = v;
    }
  }
}

// ---------------------------------------------------------------------------
// view = A[4096,2112] @ W[4096,2112]^T, 8-phase 256^2 template (m201):
// BK=64, 512 thr (2Mx4N waves, 128x64 per wave), 128 KiB dbuf LDS,
// XOR-swizzle (row&7)<<4 on both staging-source and ds_read, counted vmcnt.
// ---------------------------------------------------------------------------
__global__ __launch_bounds__(512, 2) void gemm_views(
    const unsigned short* __restrict__ triu, const unsigned short* __restrict__ tril,
    const unsigned short* __restrict__ Wu, const unsigned short* __restrict__ Wl,
    float* __restrict__ dout)
{
  __shared__ __align__(16) unsigned short lds[65536];  // [2 buf][A|B][256*64]

  const int z = blockIdx.z;
  const unsigned short* Ag = z ? tril : triu;
  const unsigned short* Bg = z ? Wl : Wu;
  float* C = dout + (size_t)16777216 * (size_t)(1 + z);

  const int tid = threadIdx.x;
  const int lane = tid & 63, wv = tid >> 6;
  const int m0 = blockIdx.y << 8, n0 = blockIdx.x << 8;

  // ---- staging geometry: per cp16 a wave covers 8 rows x 64 k (1024 B linear)
  const int lr = lane >> 3;                    // row within wave's 8-row group
  const int cuch = (lane & 7) ^ lr;            // pre-swizzled global chunk
  const int rA = wv * 8 + lr;                                  // + OFF
  const int rB = (wv & 3) * 8 + (wv >> 2) * 64 + lr;           // + OFF
  const unsigned short* gA = Ag + (size_t)(m0 + rA) * KP + cuch * 8;
  const unsigned short* gB = Bg + (size_t)(n0 + rB) * KP + cuch * 8;
  const int dA = tid * 8;                                      // u16 idx
  const int dB = (wv & 3) * 512 + (wv >> 2) * 4096 + lane * 8;

  // ---- fragment-read geometry (swizzled)
  const int fr = lane & 15, fq = lane >> 4;
  const int sx0 = ((fq ^ (fr & 7))) * 8;         // k2=0 chunk
  const int sx1 = (((4 + fq) ^ (fr & 7))) * 8;   // k2=1 chunk
  const int rowA0 = (wv >> 2) * 128 + fr;
  const int rowB0 = (wv & 3) * 64 + fr;

  f32x4 acc[8][4] = {};
  bf16x8 af0[4], af1[4], bh0[2], bh1[2];

#define STAGE_A(B_, KT, OFF) do { \
    cp16(gA + (size_t)(OFF) * KP + (KT) * 64, lds + (B_) * 32768 + (OFF) * 64 + dA); \
    cp16(gA + (size_t)((OFF) + 128) * KP + (KT) * 64, \
         lds + (B_) * 32768 + ((OFF) + 128) * 64 + dA); \
  } while (0)
#define STAGE_B(B_, KT, OFF) do { \
    cp16(gB + (size_t)(OFF) * KP + (KT) * 64, \
         lds + (B_) * 32768 + 16384 + (OFF) * 64 + dB); \
    cp16(gB + (size_t)((OFF) + 128) * KP + (KT) * 64, \
         lds + (B_) * 32768 + 16384 + ((OFF) + 128) * 64 + dB); \
  } while (0)

#define PHASE(B_, MH, NH, LA, LB, STAGE_STMT, WAIT_STMT) do { \
    if (LA) { \
      const unsigned short* pa = lds + (B_) * 32768 + ((rowA0 + (MH) * 64) << 6); \
      _Pragma("unroll") for (int mt = 0; mt < 4; ++mt) { \
        af0[mt] = ld_frag(pa + mt * 1024 + sx0); \
        af1[mt] = ld_frag(pa + mt * 1024 + sx1); } } \
    if (LB) { \
      const unsigned short* pb = lds + (B_) * 32768 + 16384 + ((rowB0 + (NH) * 32) << 6); \
      _Pragma("unroll") for (int nt = 0; nt < 2; ++nt) { \
        bh0[nt] = ld_frag(pb + nt * 1024 + sx0); \
        bh1[nt] = ld_frag(pb + nt * 1024 + sx1); } } \
    STAGE_STMT; \
    barrier_sync(); \
    __builtin_amdgcn_s_setprio(1); \
    _Pragma("unroll") for (int mt = 0; mt < 4; ++mt) \
    _Pragma("unroll") for (int nt = 0; nt < 2; ++nt) { \
      acc[(MH)*4+mt][(NH)*2+nt] = MFMA16(af0[mt], bh0[nt], acc[(MH)*4+mt][(NH)*2+nt]); \
      acc[(MH)*4+mt][(NH)*2+nt] = MFMA16(af1[mt], bh1[nt], acc[(MH)*4+mt][(NH)*2+nt]); } \
    __builtin_amdgcn_s_setprio(0); \
    WAIT_STMT; \
    barrier_sync(); \
  } while (0)

  // ---- prologue: stage tile 0 (order: A0, B0, A1, B1)
  STAGE_A(0, 0, 0);
  STAGE_B(0, 0, 0);
  STAGE_A(0, 0, 64);
  STAGE_B(0, 0, 32);
  VMWAIT(4);        // A0,B0 of tile 0 landed; A1,B1 still in flight
  barrier_sync();

  // ---- main loop: 4 phases/tile, stage tile t+1 (2 cp16/phase), counted vmcnt
  for (int t = 0; t < NT - 1; ++t) {
    const int cb = t & 1, nb = cb ^ 1, nk = t + 1;
    PHASE(cb, 0, 0, 1, 1, STAGE_A(nb, nk, 0),  VMWAIT(4));  // ensures A1(t)
    PHASE(cb, 1, 0, 1, 0, STAGE_B(nb, nk, 0),  VMWAIT(4));  // ensures B1(t)
    PHASE(cb, 1, 1, 0, 1, STAGE_A(nb, nk, 64), (void)0);
    PHASE(cb, 0, 1, 1, 0, STAGE_B(nb, nk, 32), VMWAIT(4));  // ensures A0,B0(t+1)
  }
  // ---- last tile (no staging; tightened waits)
  {
    const int cb = (NT - 1) & 1;
    PHASE(cb, 0, 0, 1, 1, (void)0, VMWAIT(2));  // ensures A1(last)
    PHASE(cb, 1, 0, 1, 0, (void)0, VMWAIT(0));  // ensures B1(last)
    PHASE(cb, 1, 1, 0, 1, (void)0, (void)0);
    PHASE(cb, 0, 1, 1, 0, (void)0, (void)0);
  }

  // ---- epilogue: acc -> C
  const int qr = fq << 2;
  const int crow = m0 + (wv >> 2) * 128 + qr;
  const int ccol = n0 + (wv & 3) * 64 + fr;
#pragma unroll
  for (int mt = 0; mt < 8; ++mt)
#pragma unroll
    for (int nt = 0; nt < 4; ++nt) {
      float* cp = C + (size_t)(crow + mt * 16) * 4096 + (ccol + nt * 16);
#pragma unroll
      for (int r = 0; r < 4; ++r) cp[(size_t)r * 4096] = acc[mt][nt][r];
    }
#undef STAGE_A
#undef STAGE_B
#undef PHASE
}

// ---------------------------------------------------------------------------
extern "C" void kernel_launch(void* const* d_in, const int* in_sizes, int n_in,
                              void* d_out, int out_size, void* d_ws, size_t ws_size,
                              hipStream_t stream) {
  const float* feat  = (const float*)d_in[0];   // [4096,64,64]
  const float* kpW   = (const float*)d_in[1];   // [64,64]
  const float* Wtriu = (const float*)d_in[2];   // [4096,2080]
  const float* Wtril = (const float*)d_in[3];   // [4096,2080]
  float* out = (float*)d_out;                   // [emb_flat | view1 | view2]

  // workspace layout (bf16, K-padded to 2112), ~69.2 MB + 8 KB
  const size_t per = (size_t)4096 * KP;
  unsigned short* triu_bf = (unsigned short*)d_ws;
  unsigned short* tril_bf = triu_bf + per;
  unsigned short* Wu_bf   = tril_bf + per;
  unsigned short* Wl_bf   = Wu_bf + per;
  unsigned short* Wt_bf   = Wl_bf + per;        // [64,64] transposed kp_W

  cvt_pad<<<dim3(1024), dim3(256), 0, stream>>>(Wtriu, Wu_bf);
  cvt_pad<<<dim3(1024), dim3(256), 0, stream>>>(Wtril, Wl_bf);
  prep_wt<<<dim3(1), dim3(256), 0, stream>>>(kpW, Wt_bf);
  batch_kp<<<dim3(4096), dim3(256), 0, stream>>>(feat, Wt_bf, out, triu_bf, tril_bf);
  gemm_views<<<dim3(16, 16, 2), dim3(512), 0, stream>>>(triu_bf, tril_bf, Wu_bf, Wl_bf, out);
}

// Round 2
// 426.485 us; speedup vs baseline: 1.1256x; 1.0060x over previous
//
#include <hip/hip_runtime.h>

typedef __bf16 bf16x8 __attribute__((ext_vector_type(8)));
typedef float f32x4 __attribute__((ext_vector_type(4)));
typedef unsigned short u16x4 __attribute__((ext_vector_type(4)));
typedef unsigned short u16x8 __attribute__((ext_vector_type(8)));

#define KP 2112   // padded K: 2080 + 32 = 33 * 64
#define NT 33     // K-tiles of 64

__device__ __forceinline__ unsigned short f2bf(float f) {
  unsigned int u = __builtin_bit_cast(unsigned int, f);
  u += 0x7FFFu + ((u >> 16) & 1u);   // round-to-nearest-even
  return (unsigned short)(u >> 16);
}

__device__ __forceinline__ bf16x8 ld_frag(const unsigned short* p) {
  return __builtin_bit_cast(bf16x8, *(const u16x8*)p);
}

#define MFMA16(a, b, c) __builtin_amdgcn_mfma_f32_16x16x32_bf16((a), (b), (c), 0, 0, 0)

// async global->LDS, 16B per lane (global_load_lds_dwordx4)
__device__ __forceinline__ void cp16(const void* g, void* l) {
  __builtin_amdgcn_global_load_lds(
      (const __attribute__((address_space(1))) unsigned int*)g,
      (__attribute__((address_space(3))) unsigned int*)l, 16, 0, 0);
}

__device__ __forceinline__ void barrier_sync() {
  asm volatile("" ::: "memory");
  __builtin_amdgcn_s_barrier();
  __builtin_amdgcn_sched_barrier(0);
}

#define VMWAIT(N) asm volatile("s_waitcnt vmcnt(" #N ")" ::: "memory")

// ---------------------------------------------------------------------------
// fp32 [4096,2080] -> bf16 [4096,2112] with zero pad (for W_triu / W_tril)
// ---------------------------------------------------------------------------
__global__ __launch_bounds__(256) void cvt_pad(const float* __restrict__ in,
                                               unsigned short* __restrict__ out) {
  const int total = 4096 * (KP / 4);           // u16x4 chunks
  int i = blockIdx.x * 256 + threadIdx.x;
  const int stride = gridDim.x * 256;
  for (; i < total; i += stride) {
    const int row = i / (KP / 4);
    const int c4 = i - row * (KP / 4);
    u16x4 o = {0, 0, 0, 0};
    if (c4 < 520) {
      float4 v = *(const float4*)(in + (size_t)row * 2080 + c4 * 4);
      o[0] = f2bf(v.x); o[1] = f2bf(v.y); o[2] = f2bf(v.z); o[3] = f2bf(v.w);
    }
    ((u16x4*)out)[i] = o;
  }
}

// ---------------------------------------------------------------------------
// One-time: Wt[c*64+d] = bf16(W[d*64+c])  (shared by all 4096 batch_kp blocks)
// ---------------------------------------------------------------------------
__global__ __launch_bounds__(256) void prep_wt(const float* __restrict__ W,
                                               unsigned short* __restrict__ Wt) {
  const int tid = threadIdx.x;
#pragma unroll
  for (int j = 0; j < 16; ++j) {
    const int o = tid * 16 + j;           // 0..4095
    const int c = o >> 6, d = o & 63;
    Wt[o] = f2bf(W[d * 64 + c]);
  }
}

// ---------------------------------------------------------------------------
// Per-batch: embs_kp = E * kp_W * E^T via bf16 MFMA; copy E to out0;
// scatter triu/tril (bf16, K-stride 2112, pad zeroed).
// ---------------------------------------------------------------------------
__global__ __launch_bounds__(256) void batch_kp(
    const float* __restrict__ E,        // [B,64,64]
    const unsigned short* __restrict__ Wt,  // [64,64] bf16 transposed
    float* __restrict__ out0,           // [B,4096]
    unsigned short* __restrict__ triu,  // [B,2112] bf16
    unsigned short* __restrict__ tril)  // [B,2112] bf16
{
  __shared__ __align__(16) unsigned short sE[64 * 64];
  __shared__ __align__(16) unsigned short sWt[64 * 64];
  __shared__ __align__(16) unsigned short sT[64 * 64];

  const int b = blockIdx.x;
  const int tid = threadIdx.x;
  const float* Eb = E + (size_t)b * 4096;
  float* o0 = out0 + (size_t)b * 4096;

  cp16(Wt + tid * 8, sWt + tid * 8);
  cp16(Wt + 2048 + tid * 8, sWt + 2048 + tid * 8);

#pragma unroll
  for (int it = 0; it < 4; ++it) {
    const int flat = it * 1024 + tid * 4;
    float4 v = *(const float4*)(Eb + flat);
    *(float4*)(o0 + flat) = v;                 // embs_flatten output (exact fp32)
    u16x4 e;
    e[0] = f2bf(v.x); e[1] = f2bf(v.y); e[2] = f2bf(v.z); e[3] = f2bf(v.w);
    *(u16x4*)(sE + flat) = e;
  }
  __syncthreads();   // drains vmcnt (cp16) + lgkm

  const int lane = tid & 63, w = tid >> 6;
  const int fr = lane & 15;
  const int fk = (lane >> 4) << 3;
  const int qr = (lane >> 4) << 2;

  // T = Ebf * Wkp : wave w computes rows [w*16, w*16+16)
#pragma unroll
  for (int ct = 0; ct < 4; ++ct) {
    f32x4 acc = {0.f, 0.f, 0.f, 0.f};
#pragma unroll
    for (int k2 = 0; k2 < 2; ++k2) {
      bf16x8 a = ld_frag(sE + (w * 16 + fr) * 64 + k2 * 32 + fk);
      bf16x8 bb = ld_frag(sWt + (ct * 16 + fr) * 64 + k2 * 32 + fk);
      acc = MFMA16(a, bb, acc);
    }
#pragma unroll
    for (int r = 0; r < 4; ++r)
      sT[(w * 16 + qr + r) * 64 + ct * 16 + fr] = f2bf(acc[r]);
  }
  __syncthreads();

  // K = T * E^T ; scatter into triu/tril.
  unsigned short* tu = triu + (size_t)b * KP;
  unsigned short* tl = tril + (size_t)b * KP;
  if (tid < 32) { tu[2080 + tid] = 0; tl[2080 + tid] = 0; }  // zero K-pad
#pragma unroll
  for (int ct = 0; ct < 4; ++ct) {
    f32x4 acc = {0.f, 0.f, 0.f, 0.f};
#pragma unroll
    for (int k2 = 0; k2 < 2; ++k2) {
      bf16x8 a = ld_frag(sT + (w * 16 + fr) * 64 + k2 * 32 + fk);
      bf16x8 bb = ld_frag(sE + (ct * 16 + fr) * 64 + k2 * 32 + fk);
      acc = MFMA16(a, bb, acc);
    }
#pragma unroll
    for (int r = 0; r < 4; ++r) {
      const int i = w * 16 + qr + r;
      const int j = ct * 16 + fr;
      const unsigned short v = f2bf(acc[r]);
      if (j >= i) tu[i * 64 - ((i * (i - 1)) >> 1) + (j - i)] = v;
      if (j <= i) tl[((i * (i + 1)) >> 1) + j] = v;
    }
  }
}

// ---------------------------------------------------------------------------
// view = A[4096,2112] @ W[4096,2112]^T, 256^2 tile, BK=64, 512 thr (2Mx4N
// waves, 128x64 per wave). 4 phases/K-tile: (MH0,k0),(MH1,k0),(MH1,k1),
// (MH0,k1); 16 MFMA each; every fragment ds_read exactly 1 phase before use
// (ping-pong reg sets); stages ~3 phases ahead; VMWAIT(4)@p2, VMWAIT(6)@p3.
// LDS XOR-swizzle (row&7) on pre-swizzled global src + swizzled ds_read.
// ---------------------------------------------------------------------------
__global__ __launch_bounds__(512, 2) void gemm_views(
    const unsigned short* __restrict__ triu, const unsigned short* __restrict__ tril,
    const unsigned short* __restrict__ Wu, const unsigned short* __restrict__ Wl,
    float* __restrict__ dout)
{
  __shared__ __align__(16) unsigned short lds[65536];  // [2 buf][A|B][256*64]

  const int z = blockIdx.z;
  const unsigned short* Ag = z ? tril : triu;
  const unsigned short* Bg = z ? Wl : Wu;
  float* C = dout + (size_t)16777216 * (size_t)(1 + z);

  const int tid = threadIdx.x;
  const int lane = tid & 63, wv = tid >> 6;
  const int m0 = blockIdx.y << 8, n0 = blockIdx.x << 8;

  // ---- staging geometry: per cp16 a wave covers 8 rows x 64 k (1024 B linear)
  const int lr = lane >> 3;                    // row within wave's 8-row group
  const int cuch = (lane & 7) ^ lr;            // pre-swizzled global chunk
  const int rA = wv * 8 + lr;                                  // + OFF
  const int rB = (wv & 3) * 8 + (wv >> 2) * 64 + lr;           // + OFF
  const unsigned short* gA = Ag + (size_t)(m0 + rA) * KP + cuch * 8;
  const unsigned short* gB = Bg + (size_t)(n0 + rB) * KP + cuch * 8;
  const int dA = tid * 8;                                      // u16 idx
  const int dB = (wv & 3) * 512 + (wv >> 2) * 4096 + lane * 8;

  // ---- fragment-read geometry (swizzled)
  const int fr = lane & 15, fq = lane >> 4;
  const int rowA0 = (wv >> 2) * 128 + fr;
  const int rowB0 = (wv & 3) * 64 + fr;

  f32x4 acc[8][4] = {};
  bf16x8 aA_[4], aB_[4], bA_[4], bB_[4];   // ping-pong fragment sets

#define STAGE_A(B_, KT, OFF) do { \
    cp16(gA + (size_t)(OFF) * KP + (KT) * 64, lds + (B_) * 32768 + (OFF) * 64 + dA); \
    cp16(gA + (size_t)((OFF) + 128) * KP + (KT) * 64, \
         lds + (B_) * 32768 + ((OFF) + 128) * 64 + dA); \
  } while (0)
#define STAGE_B(B_, KT, OFF) do { \
    cp16(gB + (size_t)(OFF) * KP + (KT) * 64, \
         lds + (B_) * 32768 + 16384 + (OFF) * 64 + dB); \
    cp16(gB + (size_t)((OFF) + 128) * KP + (KT) * 64, \
         lds + (B_) * 32768 + 16384 + ((OFF) + 128) * 64 + dB); \
  } while (0)
// read 4 A-frags (one MH-half, one k-half) / 4 B-frags (all nt, one k-half)
#define LDA(S, B_, MH, KH) do { _Pragma("unroll") \
    for (int mt = 0; mt < 4; ++mt) \
      S[mt] = ld_frag(lds + (B_) * 32768 + (rowA0 + (MH) * 64 + mt * 16) * 64 + \
                      ((((KH) * 4 + fq) ^ (fr & 7)) * 8)); \
  } while (0)
#define LDB(S, B_, KH) do { _Pragma("unroll") \
    for (int nt = 0; nt < 4; ++nt) \
      S[nt] = ld_frag(lds + (B_) * 32768 + 16384 + (rowB0 + nt * 16) * 64 + \
                      ((((KH) * 4 + fq) ^ (fr & 7)) * 8)); \
  } while (0)
#define PH_MFMA(AS, BS, MH) do { \
    __builtin_amdgcn_s_setprio(1); \
    _Pragma("unroll") for (int mt = 0; mt < 4; ++mt) \
    _Pragma("unroll") for (int nt = 0; nt < 4; ++nt) \
      acc[(MH) * 4 + mt][nt] = MFMA16(AS[mt], BS[nt], acc[(MH) * 4 + mt][nt]); \
    __builtin_amdgcn_s_setprio(0); \
  } while (0)

  // ---- prologue: tile 0 fully + tile 1 {B0,B32,A0}; then first frag reads
  STAGE_A(0, 0, 0);
  STAGE_B(0, 0, 0);
  STAGE_B(0, 0, 32);
  STAGE_A(0, 0, 64);
  STAGE_B(1, 1, 0);
  STAGE_B(1, 1, 32);
  STAGE_A(1, 1, 0);
  VMWAIT(6);           // tile-0 bundles (8 cp16) landed; tile-1 (6) in flight
  barrier_sync();
  LDA(aB_, 0, 0, 0);   // a[MH0,k0](0)
  LDB(bA_, 0, 0);      // b[k0](0)

  for (int t = 0; t < NT; ++t) {
    const int cb = t & 1, nb = cb ^ 1;
    const int t1 = (t + 1 < NT) ? t + 1 : NT - 1;   // clamp keeps vmcnt uniform
    const int t2 = (t + 2 < NT) ? t + 2 : NT - 1;
    // p0: compute (MH0,k0) [aB_,bA_]; read a[MH1,k0](t); stage SA(t+1,64)
    LDA(aA_, cb, 1, 0);
    STAGE_A(nb, t1, 64);
    barrier_sync();
    PH_MFMA(aB_, bA_, 0);
    barrier_sync();
    // p1: compute (MH1,k0) [aA_,bA_]; read a[MH1,k1](t) + b[k1](t)
    LDA(aB_, cb, 1, 1);
    LDB(bB_, cb, 1);
    barrier_sync();
    PH_MFMA(aA_, bA_, 1);
    barrier_sync();
    // p2: compute (MH1,k1) [aB_,bB_]; read a[MH0,k1](t); stage SB(t+2,0)
    LDA(aA_, cb, 0, 1);
    STAGE_B(cb, t2, 0);
    barrier_sync();
    PH_MFMA(aB_, bB_, 1);
    VMWAIT(4);   // clears SB(t+1,0), SB(t+1,32), SA(t+1,0) for p3's reads
    barrier_sync();
    // p3: compute (MH0,k1) [aA_,bB_]; read a[MH0,k0](t+1) + b[k0](t+1);
    //     stage SB(t+2,32) + SA(t+2,0)
    LDA(aB_, nb, 0, 0);
    LDB(bA_, nb, 0);
    STAGE_B(cb, t2, 32);
    STAGE_A(cb, t2, 0);
    barrier_sync();
    PH_MFMA(aA_, bB_, 0);
    VMWAIT(6);   // clears SA(t+1,64) for next p0's read
    barrier_sync();
  }

  // ---- epilogue: acc -> C
  const int qr = fq << 2;
  const int crow = m0 + (wv >> 2) * 128 + qr;
  const int ccol = n0 + (wv & 3) * 64 + fr;
#pragma unroll
  for (int mt = 0; mt < 8; ++mt)
#pragma unroll
    for (int nt = 0; nt < 4; ++nt) {
      float* cp = C + (size_t)(crow + mt * 16) * 4096 + (ccol + nt * 16);
#pragma unroll
      for (int r = 0; r < 4; ++r) cp[(size_t)r * 4096] = acc[mt][nt][r];
    }
#undef STAGE_A
#undef STAGE_B
#undef LDA
#undef LDB
#undef PH_MFMA
}

// ---------------------------------------------------------------------------
extern "C" void kernel_launch(void* const* d_in, const int* in_sizes, int n_in,
                              void* d_out, int out_size, void* d_ws, size_t ws_size,
                              hipStream_t stream) {
  const float* feat  = (const float*)d_in[0];   // [4096,64,64]
  const float* kpW   = (const float*)d_in[1];   // [64,64]
  const float* Wtriu = (const float*)d_in[2];   // [4096,2080]
  const float* Wtril = (const float*)d_in[3];   // [4096,2080]
  float* out = (float*)d_out;                   // [emb_flat | view1 | view2]

  // workspace layout (bf16, K-padded to 2112), ~69.2 MB + 8 KB
  const size_t per = (size_t)4096 * KP;
  unsigned short* triu_bf = (unsigned short*)d_ws;
  unsigned short* tril_bf = triu_bf + per;
  unsigned short* Wu_bf   = tril_bf + per;
  unsigned short* Wl_bf   = Wu_bf + per;
  unsigned short* Wt_bf   = Wl_bf + per;        // [64,64] transposed kp_W

  cvt_pad<<<dim3(1024), dim3(256), 0, stream>>>(Wtriu, Wu_bf);
  cvt_pad<<<dim3(1024), dim3(256), 0, stream>>>(Wtril, Wl_bf);
  prep_wt<<<dim3(1), dim3(256), 0, stream>>>(kpW, Wt_bf);
  batch_kp<<<dim3(4096), dim3(256), 0, stream>>>(feat, Wt_bf, out, triu_bf, tril_bf);
  gemm_views<<<dim3(16, 16, 2), dim3(512), 0, stream>>>(triu_bf, tril_bf, Wu_bf, Wl_bf, out);
}